// Round 4
// baseline (324.671 us; speedup 1.0000x reference)
//
#include <hip/hip_runtime.h>
#include <cstdint>

#define N 8192
#define BLK 512          // 8 waves/block
#define NBLK 1024        // pairs p = b + pp*NBLK, pp=0..3
#define C2_LEN 33550336  // C(8192,2)
#define C2_QUADS (C2_LEN / 4)

// Block b, phase pp handles row-pair {p, 8190-p}, combined length exactly N.
// Per phase: all 8 float4 c2 loads (4 per row) issued up front (predicated by
// zeroing, indices clamped in-bounds) to maximize memory-level parallelism,
// then the FMA chains. x is LDS-resident, deinterleaved xs[i&3][i>>2]
// (lane-stride-1 per read -> conflict-free).

__global__ __launch_bounds__(BLK, 4) void ham_main(const float* __restrict__ x,
                                                   const float* __restrict__ coeffs,
                                                   float* __restrict__ ws) {
    __shared__ float xs[4][2048];        // 32 KB
    __shared__ float smem[BLK / 64];
    const int t = threadIdx.x;
    const int b = blockIdx.x;
    const float* __restrict__ c1 = coeffs;
    const float* __restrict__ c2 = coeffs + N;
    const float4* __restrict__ cq = (const float4*)c2;

    {
        const float4* __restrict__ x4 = (const float4*)x;
        #pragma unroll
        for (int k = 0; k < 4; ++k) {
            const int m = t + k * BLK;
            const float4 v = x4[m];
            xs[0][m] = v.x; xs[1][m] = v.y; xs[2][m] = v.z; xs[3][m] = v.w;
        }
    }
    __syncthreads();

    float acc = 0.0f;

    #pragma unroll
    for (int pp = 0; pp < 4; ++pp) {
        const int p  = b + pp * NBLK;
        const int i1 = p;                // row A, length >= 4096
        const int i2 = N - 2 - p;        // row B, length p+1 (skip if == i1)
        const bool hasB = (i2 > i1);

        // Row A descriptor
        const int O1 = (i1 * (2 * N - i1 - 1)) >> 1;
        const int L1 = N - 1 - i1;
        int pro1 = (4 - (O1 & 3)) & 3; if (pro1 > L1) pro1 = L1;
        const int R1 = L1 - pro1, V1 = R1 >> 2, tl1 = R1 & 3;
        const int q1 = (O1 + pro1) >> 2;
        const int xbA = i1 + 1 + pro1;

        // Row B descriptor (degenerate when !hasB -> V2=0, edges masked off)
        int O2 = 0, pro2 = 0, V2 = 0, tl2 = 0, q2 = 0, xbB = i2 + 1;
        if (hasB) {
            O2 = (i2 * (2 * N - i2 - 1)) >> 1;
            const int L2 = N - 1 - i2;
            pro2 = (4 - (O2 & 3)) & 3; if (pro2 > L2) pro2 = L2;
            const int R2 = L2 - pro2; V2 = R2 >> 2; tl2 = R2 & 3;
            q2 = (O2 + pro2) >> 2;
            xbB = i2 + 1 + pro2;
        }

        // ---- Issue all 8 vector loads up front (masked by zeroing) ----
        float4 ca[4], cb[4];
        int xia[4], xib[4];
        #pragma unroll
        for (int k = 0; k < 4; ++k) {
            const int idx = t + k * BLK;
            const bool mA = idx < V1;
            const int iA = mA ? idx : 0;               // q1+idx always in-bounds when mA
            ca[k] = cq[q1 + iA];
            if (!mA) ca[k] = make_float4(0.f, 0.f, 0.f, 0.f);
            xia[k] = min(xbA + (iA << 2), N - 4);      // clamp: masked lanes stay in xs

            const bool mB = idx < V2;
            const int iB = mB ? idx : 0;
            int qb = q2 + iB; qb = min(qb, C2_QUADS - 1);  // V2==0 rows: q2 may be array end
            cb[k] = cq[qb];
            if (!mB) cb[k] = make_float4(0.f, 0.f, 0.f, 0.f);
            xib[k] = min(xbB + (iB << 2), N - 4);
        }

        // ---- Edge scalars (tiny, L1/L2-hit) while vector loads are in flight ----
        float sA = 0.0f, sB = 0.0f;
        if (t < pro1) { const int xi = i1 + 1 + t;            sA += c2[O1 + t] * xs[xi & 3][xi >> 2]; }
        if (t < tl1)  { const int e = (V1 << 2) + t; const int xi = xbA + e; sA += c2[O1 + pro1 + e] * xs[xi & 3][xi >> 2]; }
        if (t < pro2) { const int xi = i2 + 1 + t;            sB += c2[O2 + t] * xs[xi & 3][xi >> 2]; }
        if (t < tl2)  { const int e = (V2 << 2) + t; const int xi = xbB + e; sB += c2[O2 + pro2 + e] * xs[xi & 3][xi >> 2]; }

        // ---- FMA chains ----
        #pragma unroll
        for (int k = 0; k < 4; ++k) {
            const int a0 = xia[k];
            sA += ca[k].x * xs[a0 & 3][a0 >> 2]
                + ca[k].y * xs[(a0 + 1) & 3][(a0 + 1) >> 2]
                + ca[k].z * xs[(a0 + 2) & 3][(a0 + 2) >> 2]
                + ca[k].w * xs[(a0 + 3) & 3][(a0 + 3) >> 2];
            const int b0 = xib[k];
            sB += cb[k].x * xs[b0 & 3][b0 >> 2]
                + cb[k].y * xs[(b0 + 1) & 3][(b0 + 1) >> 2]
                + cb[k].z * xs[(b0 + 2) & 3][(b0 + 2) >> 2]
                + cb[k].w * xs[(b0 + 3) & 3][(b0 + 3) >> 2];
        }

        const float xA = xs[i1 & 3][i1 >> 2];
        const float xB = hasB ? xs[i2 & 3][i2 >> 2] : 0.0f;
        acc += xA * sA + xB * sB;
    }

    // Degree-1 terms: 8 per block
    if (t < 8) {
        const int g = (b << 3) + t;
        acc += c1[g] * xs[g & 3][g >> 2];
    }

    // Block reduction
    #pragma unroll
    for (int o = 32; o > 0; o >>= 1) acc += __shfl_down(acc, o, 64);
    const int wave = t >> 6;
    const int lane = t & 63;
    if (lane == 0) smem[wave] = acc;
    __syncthreads();
    if (t == 0) {
        float v = 0.0f;
        #pragma unroll
        for (int w = 0; w < BLK / 64; ++w) v += smem[w];
        ws[b] = v;
    }
}

__global__ __launch_bounds__(256) void ham_reduce(const float* __restrict__ ws,
                                                  float* __restrict__ out) {
    const int t = threadIdx.x;
    const float4* __restrict__ w4 = (const float4*)ws;   // 1024 floats
    const float4 v4 = w4[t];
    float v = v4.x + v4.y + v4.z + v4.w;
    #pragma unroll
    for (int o = 32; o > 0; o >>= 1) v += __shfl_down(v, o, 64);
    __shared__ float smem[4];
    const int wave = t >> 6;
    const int lane = t & 63;
    if (lane == 0) smem[wave] = v;
    __syncthreads();
    if (t == 0) out[0] = smem[0] + smem[1] + smem[2] + smem[3];
}

extern "C" void kernel_launch(void* const* d_in, const int* in_sizes, int n_in,
                              void* d_out, int out_size, void* d_ws, size_t ws_size,
                              hipStream_t stream) {
    const float* x      = (const float*)d_in[0];
    const float* coeffs = (const float*)d_in[1];
    float* out = (float*)d_out;
    float* ws  = (float*)d_ws;

    ham_main<<<NBLK, BLK, 0, stream>>>(x, coeffs, ws);
    ham_reduce<<<1, 256, 0, stream>>>(ws, out);
}

// Round 5
// 201.307 us; speedup vs baseline: 1.6128x; 1.6128x over previous
//
#include <hip/hip_runtime.h>
#include <cstdint>

#define N 8192
#define BLK 512         // threads per block (8 waves)
#define NBLK 1024       // 4 blocks/CU x 256 CU

// Reverted to the round-2 structure (known-good, ~25us marginal kernel time,
// 5.4 TB/s on the L3-resident 134 MB coeffs stream). Round-4's 8-deep
// load-prefetch variant spilled to scratch (VGPR=64, 323 MB scratch writes,
// 192us) and is abandoned: the 5.4 TB/s plateau across two independent
// structures is a fabric/L3 read ceiling, not exposed latency.

__device__ __forceinline__ float row_partial(const float* __restrict__ c2,
                                             const float (&xs)[4][2048],
                                             int O, int L, int i) {
    const int t = threadIdx.x;
    const float* cp = c2 + O;
    const int xb0 = i + 1;
    float s = 0.0f;

    int pro = (4 - (O & 3)) & 3;          // scalars until c2 is 16B-aligned
    if (pro > L) pro = L;
    if (t < pro) {
        const int xi = xb0 + t;
        s += cp[t] * xs[xi & 3][xi >> 2];
    }

    const int R = L - pro;
    const int V = R >> 2;
    const int tail = R & 3;
    const float4* __restrict__ cv = (const float4*)(cp + pro);
    const int xb = xb0 + pro;

    for (int v = t; v < V; v += BLK) {
        const float4 c = cv[v];
        const int xi = xb + (v << 2);
        const float x0 = xs[xi & 3][xi >> 2];
        const float x1 = xs[(xi + 1) & 3][(xi + 1) >> 2];
        const float x2 = xs[(xi + 2) & 3][(xi + 2) >> 2];
        const float x3 = xs[(xi + 3) & 3][(xi + 3) >> 2];
        s += c.x * x0 + c.y * x1 + c.z * x2 + c.w * x3;
    }
    if (t < tail) {
        const int e = (V << 2) + t;
        const int xi = xb + e;
        s += cp[pro + e] * xs[xi & 3][xi >> 2];
    }
    return s;
}

__global__ __launch_bounds__(BLK) void ham_main(const float* __restrict__ x,
                                                const float* __restrict__ coeffs,
                                                float* __restrict__ ws) {
    __shared__ float xs[4][2048];         // 32 KB: x[i] -> xs[i&3][i>>2]
    const int t = threadIdx.x;
    const int b = blockIdx.x;
    const float* __restrict__ c1 = coeffs;
    const float* __restrict__ c2 = coeffs + N;

    {
        const float4* __restrict__ x4 = (const float4*)x;
        for (int k = t; k < 2048; k += BLK) {
            const float4 v = x4[k];
            xs[0][k] = v.x; xs[1][k] = v.y; xs[2][k] = v.z; xs[3][k] = v.w;
        }
    }
    __syncthreads();

    float acc = 0.0f;

    #pragma unroll
    for (int pp = 0; pp < 4; ++pp) {
        const int p = b + pp * NBLK;      // row-pair index
        const int i1 = p;
        const int O1 = (i1 * (2 * N - i1 - 1)) >> 1;
        acc += xs[i1 & 3][i1 >> 2] * row_partial(c2, xs, O1, N - 1 - i1, i1);

        const int i2 = N - 2 - p;
        if (i2 > i1) {
            const int O2 = (i2 * (2 * N - i2 - 1)) >> 1;
            acc += xs[i2 & 3][i2 >> 2] * row_partial(c2, xs, O2, N - 1 - i2, i2);
        }
    }

    if (t < 8) {
        const int g = (b << 3) + t;
        acc += c1[g] * xs[g & 3][g >> 2];
    }

    #pragma unroll
    for (int o = 32; o > 0; o >>= 1) acc += __shfl_down(acc, o, 64);
    __shared__ float smem[BLK / 64];
    const int wave = t >> 6;
    const int lane = t & 63;
    if (lane == 0) smem[wave] = acc;
    __syncthreads();
    if (t == 0) {
        float v = 0.0f;
        #pragma unroll
        for (int w = 0; w < BLK / 64; ++w) v += smem[w];
        ws[b] = v;
    }
}

__global__ __launch_bounds__(256) void ham_reduce(const float* __restrict__ ws,
                                                  float* __restrict__ out) {
    const int t = threadIdx.x;
    const float4* __restrict__ w4 = (const float4*)ws;
    const float4 v4 = w4[t];
    float v = v4.x + v4.y + v4.z + v4.w;
    #pragma unroll
    for (int o = 32; o > 0; o >>= 1) v += __shfl_down(v, o, 64);
    __shared__ float smem[4];
    const int wave = t >> 6;
    const int lane = t & 63;
    if (lane == 0) smem[wave] = v;
    __syncthreads();
    if (t == 0) out[0] = smem[0] + smem[1] + smem[2] + smem[3];
}

extern "C" void kernel_launch(void* const* d_in, const int* in_sizes, int n_in,
                              void* d_out, int out_size, void* d_ws, size_t ws_size,
                              hipStream_t stream) {
    const float* x      = (const float*)d_in[0];
    const float* coeffs = (const float*)d_in[1];
    float* out = (float*)d_out;
    float* ws  = (float*)d_ws;

    ham_main<<<NBLK, BLK, 0, stream>>>(x, coeffs, ws);
    ham_reduce<<<1, 256, 0, stream>>>(ws, out);
}